// Round 5
// baseline (927.997 us; speedup 1.0000x reference)
//
#include <hip/hip_runtime.h>

using f32x4  = __attribute__((ext_vector_type(4))) float;
using bf16x8 = __attribute__((ext_vector_type(8))) __bf16;

#define L_SEQ 1024
#define D_MODEL 1536
#define D_INNER 3072
#define DT_RANK 96
#define D_STATE 16

// Static fallback scratch: 4 x [1024][3072] f32 + [1024][128] f32 = 50.86 MB.
#define SCRATCH_FLOATS (4 * L_SEQ * D_INNER + L_SEQ * 128)
__device__ __align__(16) float g_scratch[SCRATCH_FLOATS];

// ---------------------------------------------------------------------------
// BT GEMM, all-f32 I/O: C[M][N] = sum_k A[M][K] * B[N][K]  (B is N-major f32)
// Staging converts f32 -> bf16 in LDS. AMODE/BMODE: 1 = plain bf16;
// 2 = (hi,lo) bf16 pair -> 3 MFMAs per k-tile (f32-accurate products).
// EPI: 0 = split store (x|z); 1 = softplus(acc+bias); 2 = atomicAdd (split-K);
//      3 = store with non-finite sentinel (diagnostic).  All f32 stores.
// ---------------------------------------------------------------------------
template <int BM, int BN, int BK, int AMODE, int BMODE, int EPI>
__global__ __launch_bounds__(256) void gemm_bt(
    const float* __restrict__ Ap, const float* __restrict__ Bp,
    float* __restrict__ out0, float* __restrict__ out1,
    const float* __restrict__ bias,
    int M, int N, int K, int lda, int ldb, int ldc)
{
    constexpr int LDSK = BK + 8;   // 80B row stride: 16B-aligned, 2-way banks (free)
    constexpr int WM = BM / 2, WN = BN / 2;
    constexpr int FM = WM / 16, FN = WN / 16;
    __shared__ __align__(16) __bf16 As [BM * LDSK];
    __shared__ __align__(16) __bf16 As2[(AMODE == 2) ? BM * LDSK : 8];
    __shared__ __align__(16) __bf16 Bs [BN * LDSK];
    __shared__ __align__(16) __bf16 Bs2[(BMODE == 2) ? BN * LDSK : 8];

    const int tid  = threadIdx.x;
    const int lane = tid & 63;
    const int wid  = tid >> 6;
    const int wm = wid >> 1, wn = wid & 1;
    const int m0 = blockIdx.x * BM, n0 = blockIdx.y * BN;

    const int nkt = (K + BK - 1) / BK;
    const int per = (nkt + (int)gridDim.z - 1) / (int)gridDim.z;
    const int kb  = blockIdx.z * per * BK;
    const int ke  = min(K, kb + per * BK);

    f32x4 acc[FM][FN];
#pragma unroll
    for (int i = 0; i < FM; ++i)
#pragma unroll
        for (int j = 0; j < FN; ++j) acc[i][j] = f32x4{0.f, 0.f, 0.f, 0.f};

    const int fr = lane & 15, kq = lane >> 4;

    for (int kt = kb; kt < ke; kt += BK) {
        __syncthreads();
        // ---- stage A (BM x BK): f32 -> bf16 (hi[, lo]) ----
        {
            constexpr int CH = (BM * BK / 256) / 8;
#pragma unroll
            for (int i = 0; i < CH; ++i) {
                int c = tid * CH + i;
                int r = c / (BK / 8), kc = c % (BK / 8);
                const float* src = Ap + (size_t)(m0 + r) * lda + kt + kc * 8;
                f32x4 v0 = *(const f32x4*)src;
                f32x4 v1 = *(const f32x4*)(src + 4);
                bf16x8 hv;
#pragma unroll
                for (int e = 0; e < 4; ++e) {
                    hv[e]     = (__bf16)v0[e];
                    hv[4 + e] = (__bf16)v1[e];
                }
                *(bf16x8*)&As[r * LDSK + kc * 8] = hv;
                if constexpr (AMODE == 2) {
                    bf16x8 lv;
#pragma unroll
                    for (int e = 0; e < 4; ++e) {
                        lv[e]     = (__bf16)(v0[e] - (float)hv[e]);
                        lv[4 + e] = (__bf16)(v1[e] - (float)hv[4 + e]);
                    }
                    *(bf16x8*)&As2[r * LDSK + kc * 8] = lv;
                }
            }
        }
        // ---- stage B (BN x BK): f32 -> bf16 (hi[, lo]) ----
        {
            constexpr int CH = (BN * BK / 256) / 8;
#pragma unroll
            for (int i = 0; i < CH; ++i) {
                int c = tid * CH + i;
                int r = c / (BK / 8), kc = c % (BK / 8);
                const float* src = Bp + (size_t)(n0 + r) * ldb + kt + kc * 8;
                f32x4 v0 = *(const f32x4*)src;
                f32x4 v1 = *(const f32x4*)(src + 4);
                bf16x8 hv;
#pragma unroll
                for (int e = 0; e < 4; ++e) {
                    hv[e]     = (__bf16)v0[e];
                    hv[4 + e] = (__bf16)v1[e];
                }
                *(bf16x8*)&Bs[r * LDSK + kc * 8] = hv;
                if constexpr (BMODE == 2) {
                    bf16x8 lv;
#pragma unroll
                    for (int e = 0; e < 4; ++e) {
                        lv[e]     = (__bf16)(v0[e] - (float)hv[e]);
                        lv[4 + e] = (__bf16)(v1[e] - (float)hv[4 + e]);
                    }
                    *(bf16x8*)&Bs2[r * LDSK + kc * 8] = lv;
                }
            }
        }
        __syncthreads();
        // ---- fragments + MFMA ----
        bf16x8 af[FM], bfg[FN];
#pragma unroll
        for (int fm = 0; fm < FM; ++fm)
            af[fm] = *(const bf16x8*)&As[(wm * WM + fm * 16 + fr) * LDSK + kq * 8];
#pragma unroll
        for (int fn = 0; fn < FN; ++fn)
            bfg[fn] = *(const bf16x8*)&Bs[(wn * WN + fn * 16 + fr) * LDSK + kq * 8];
        if constexpr (AMODE == 2 && BMODE == 2) {
            bf16x8 al[FM], bl[FN];
#pragma unroll
            for (int fm = 0; fm < FM; ++fm)
                al[fm] = *(const bf16x8*)&As2[(wm * WM + fm * 16 + fr) * LDSK + kq * 8];
#pragma unroll
            for (int fn = 0; fn < FN; ++fn)
                bl[fn] = *(const bf16x8*)&Bs2[(wn * WN + fn * 16 + fr) * LDSK + kq * 8];
#pragma unroll
            for (int fm = 0; fm < FM; ++fm)
#pragma unroll
                for (int fn = 0; fn < FN; ++fn) {
                    acc[fm][fn] = __builtin_amdgcn_mfma_f32_16x16x32_bf16(
                        al[fm], bfg[fn], acc[fm][fn], 0, 0, 0);
                    acc[fm][fn] = __builtin_amdgcn_mfma_f32_16x16x32_bf16(
                        af[fm], bl[fn], acc[fm][fn], 0, 0, 0);
                    acc[fm][fn] = __builtin_amdgcn_mfma_f32_16x16x32_bf16(
                        af[fm], bfg[fn], acc[fm][fn], 0, 0, 0);
                }
        } else {
#pragma unroll
            for (int fm = 0; fm < FM; ++fm)
#pragma unroll
                for (int fn = 0; fn < FN; ++fn)
                    acc[fm][fn] = __builtin_amdgcn_mfma_f32_16x16x32_bf16(
                        af[fm], bfg[fn], acc[fm][fn], 0, 0, 0);
        }
    }

    const int rbase = m0 + wm * WM, cbase = n0 + wn * WN;
#pragma unroll
    for (int fm = 0; fm < FM; ++fm) {
#pragma unroll
        for (int fn = 0; fn < FN; ++fn) {
            int row = rbase + fm * 16 + (lane >> 4) * 4;
            int col = cbase + fn * 16 + (lane & 15);
            f32x4 v = acc[fm][fn];
            if (EPI == 0) {
                int split = N / 2;
                float* d = (col < split) ? out0 : out1;
                int cc = (col < split) ? col : col - split;
#pragma unroll
                for (int j = 0; j < 4; ++j) d[(size_t)(row + j) * ldc + cc] = v[j];
            } else if (EPI == 1) {
                float bz = bias[col];
#pragma unroll
                for (int j = 0; j < 4; ++j) {
                    float t = v[j] + bz;
                    t = (t > 20.f) ? t : log1pf(__expf(t));
                    out0[(size_t)(row + j) * ldc + col] = t;
                }
            } else if (EPI == 2) {
#pragma unroll
                for (int j = 0; j < 4; ++j)
                    atomicAdd(&out0[(size_t)(row + j) * ldc + col], v[j]);
            } else {
#pragma unroll
                for (int j = 0; j < 4; ++j) {
                    float t = v[j];
                    if (!(fabsf(t) < 1e30f)) t = 30000.0f;   // NaN/inf sentinel
                    out0[(size_t)(row + j) * ldc + col] = t;
                }
            }
        }
    }
}

// ---------------------------------------------------------------------------
__global__ __launch_bounds__(256) void zero_f32(float* __restrict__ p, int n4)
{
    int i = blockIdx.x * 256 + threadIdx.x;
    if (i < n4) ((f32x4*)p)[i] = f32x4{0.f, 0.f, 0.f, 0.f};
}

// ---------------------------------------------------------------------------
// Depthwise conv (width 4, left-pad 3) + SiLU.  x, xc: [L][D_INNER] f32.
// conv_state[d][j] = x[1020+j][d], f32.
// ---------------------------------------------------------------------------
__global__ __launch_bounds__(256) void conv_silu(
    const float* __restrict__ x, const float* __restrict__ cw,
    const float* __restrict__ cb, float* __restrict__ xc,
    float* __restrict__ conv_state)
{
    int idx = blockIdx.x * 256 + threadIdx.x;     // 1024*768 quads
    int l  = idx / (D_INNER / 4);
    int d4 = (idx % (D_INNER / 4)) * 4;
    const f32x4 zero = f32x4{0.f, 0.f, 0.f, 0.f};
    f32x4 x0 = *(const f32x4*)&x[(size_t)l * D_INNER + d4];
    f32x4 x1 = (l >= 1) ? *(const f32x4*)&x[(size_t)(l - 1) * D_INNER + d4] : zero;
    f32x4 x2 = (l >= 2) ? *(const f32x4*)&x[(size_t)(l - 2) * D_INNER + d4] : zero;
    f32x4 x3 = (l >= 3) ? *(const f32x4*)&x[(size_t)(l - 3) * D_INNER + d4] : zero;
    f32x4 r;
#pragma unroll
    for (int i = 0; i < 4; ++i) {
        int d = d4 + i;
        float w0 = cw[d * 4 + 0], w1 = cw[d * 4 + 1];
        float w2 = cw[d * 4 + 2], w3 = cw[d * 4 + 3];
        float v = cb[d] + w3 * x0[i] + w2 * x1[i] + w1 * x2[i] + w0 * x3[i];
        r[i] = v / (1.f + __expf(-v));
    }
    *(f32x4*)&xc[(size_t)l * D_INNER + d4] = r;
    if (l == L_SEQ - 1) {
#pragma unroll
        for (int i = 0; i < 4; ++i) {
            int d = d4 + i;
            conv_state[d * 4 + 3] = x0[i];
            conv_state[d * 4 + 2] = x1[i];
            conv_state[d * 4 + 1] = x2[i];
            conv_state[d * 4 + 0] = x3[i];
        }
    }
}

// ---------------------------------------------------------------------------
// Selective scan. Thread = (d, n). 16-lane shfl reduce over n. All f32.
// ---------------------------------------------------------------------------
__global__ __launch_bounds__(256) void scan_kernel(
    const float* __restrict__ delta, const float* __restrict__ xc,
    const float* __restrict__ z, const float* __restrict__ dbl,
    const float* __restrict__ A_log, const float* __restrict__ Dp,
    float* __restrict__ y, float* __restrict__ last_state)
{
    int t = blockIdx.x * 256 + threadIdx.x;
    int d = t >> 4, n = t & 15;
    float a  = __expf(A_log[d * D_STATE + n]);
    float Dv = Dp[d];
    float h = 0.f;
    for (int l = 0; l < L_SEQ; ++l) {
        float dl  = delta[(size_t)l * D_INNER + d];
        float xcv = xc[(size_t)l * D_INNER + d];
        float Bv  = dbl[l * 128 + DT_RANK + n];
        float Cv  = dbl[l * 128 + DT_RANK + D_STATE + n];
        float dA  = __expf(-dl * a);
        h = fmaf(dA, h, dl * Bv * xcv);
        float yv = h * Cv;
        yv += __shfl_xor(yv, 8);
        yv += __shfl_xor(yv, 4);
        yv += __shfl_xor(yv, 2);
        yv += __shfl_xor(yv, 1);
        if (n == 0) {
            float zv = z[(size_t)l * D_INNER + d];
            float sz = zv / (1.f + __expf(-zv));
            y[(size_t)l * D_INNER + d] = (yv + Dv * xcv) * sz;
        }
    }
    last_state[t] = h;
}

// ---------------------------------------------------------------------------
extern "C" void kernel_launch(void* const* d_in, const int* in_sizes, int n_in,
                              void* d_out, int out_size, void* d_ws, size_t ws_size,
                              hipStream_t stream)
{
    const float* hs    = (const float*)d_in[0];
    const float* Win   = (const float*)d_in[1];
    const float* cw    = (const float*)d_in[2];
    const float* cb    = (const float*)d_in[3];
    const float* Wx    = (const float*)d_in[4];
    const float* Wdt   = (const float*)d_in[5];
    const float* dtb   = (const float*)d_in[6];
    const float* Wout  = (const float*)d_in[7];
    const float* A_log = (const float*)d_in[8];
    const float* Dp    = (const float*)d_in[9];

    float* out        = (float*)d_out;                       // [1024][1536]
    float* conv_state = out + (size_t)L_SEQ * D_MODEL;       // [3072][4]
    float* last_state = conv_state + (size_t)D_INNER * 4;    // [3072][16]

    // Scratch: prefer d_ws when big enough; else static fallback.
    const size_t NEED = sizeof(float) * (size_t)SCRATCH_FLOATS;
    float* base;
    if (ws_size >= NEED) {
        base = (float*)d_ws;
    } else {
        void* sp = nullptr;
        hipGetSymbolAddress(&sp, HIP_SYMBOL(g_scratch));
        base = (float*)sp;
    }
    float* buf0 = base;                                // x -> delta
    float* buf1 = buf0 + (size_t)L_SEQ * D_INNER;      // z
    float* buf2 = buf1 + (size_t)L_SEQ * D_INNER;      // xc
    float* buf3 = buf2 + (size_t)L_SEQ * D_INNER;      // y
    float* dbl  = buf3 + (size_t)L_SEQ * D_INNER;      // [1024][128] dt|B|C

    // zero dbl (atomic split-K target)
    zero_f32<<<dim3((L_SEQ * 128 / 4 + 255) / 256), 256, 0, stream>>>(dbl, L_SEQ * 128 / 4);

    // K1: xz = hs @ Win^T  -> x (buf0), z (buf1)
    gemm_bt<128, 128, 32, 1, 1, 0><<<dim3(8, 48, 1), 256, 0, stream>>>(
        hs, Win, buf0, buf1, nullptr, L_SEQ, 2 * D_INNER, D_MODEL, D_MODEL, D_MODEL, D_INNER);

    // K2: conv + silu -> xc (buf2); conv_state
    conv_silu<<<dim3(L_SEQ * D_INNER / 4 / 256), 256, 0, stream>>>(buf0, cw, cb, buf2, conv_state);

    // K3: x_dbl = xc @ Wx^T -> dbl (hi/lo both sides, split-K 12, atomic)
    gemm_bt<128, 128, 32, 2, 2, 2><<<dim3(8, 1, 12), 256, 0, stream>>>(
        buf2, Wx, dbl, nullptr, nullptr, L_SEQ, 128, D_INNER, D_INNER, D_INNER, 128);

    // K4: delta = softplus(dt @ Wdt^T + b) -> buf0 (x dead; hi/lo both sides)
    gemm_bt<128, 128, 32, 2, 2, 1><<<dim3(8, 24, 1), 256, 0, stream>>>(
        dbl, Wdt, buf0, nullptr, dtb, L_SEQ, D_INNER, DT_RANK, 128, DT_RANK, D_INNER);

    // K5: scan -> y (buf3), last_state
    scan_kernel<<<dim3(D_INNER * D_STATE / 256), 256, 0, stream>>>(
        buf0, buf2, buf1, dbl, A_log, Dp, buf3, last_state);

    // K7: out = y @ Wout^T -> f32 out (sentinel-scrubbed)
    gemm_bt<128, 64, 32, 1, 1, 3><<<dim3(8, 24, 1), 256, 0, stream>>>(
        buf3, Wout, out, nullptr, nullptr, L_SEQ, D_MODEL, D_INNER, D_INNER, D_INNER, D_MODEL);
}

// Round 6
// 351.188 us; speedup vs baseline: 2.6425x; 2.6425x over previous
//
#include <hip/hip_runtime.h>

using f32x4  = __attribute__((ext_vector_type(4))) float;
using bf16x8 = __attribute__((ext_vector_type(8))) __bf16;

#define L_SEQ 1024
#define D_MODEL 1536
#define D_INNER 3072
#define DT_RANK 96
#define D_STATE 16

#define SCAN_NC 16          // chunks over L
#define SCAN_CL (L_SEQ / SCAN_NC)
#define NCHAIN  (D_INNER * D_STATE)   // 49152 (d,n) chains

// Static fallback scratch: 4 x [1024][3072] + [1024][128] + 3 x [NC][49152] f32.
#define SCRATCH_FLOATS (4 * L_SEQ * D_INNER + L_SEQ * 128 + 3 * SCAN_NC * NCHAIN)
__device__ __align__(16) float g_scratch[SCRATCH_FLOATS];

// ---------------------------------------------------------------------------
// BT GEMM, all-f32 I/O: C[M][N] = sum_k A[M][K] * B[N][K]  (B is N-major f32)
// Staging converts f32 -> bf16 in LDS. AMODE/BMODE: 1 = plain bf16;
// 2 = (hi,lo) bf16 pair -> 3 MFMAs per k-tile (f32-accurate products).
// EPI: 0 = split store (x|z); 1 = softplus(acc+bias); 2 = atomicAdd (split-K);
//      3 = store with non-finite sentinel (diagnostic).  All f32 stores.
// ---------------------------------------------------------------------------
template <int BM, int BN, int BK, int AMODE, int BMODE, int EPI>
__global__ __launch_bounds__(256) void gemm_bt(
    const float* __restrict__ Ap, const float* __restrict__ Bp,
    float* __restrict__ out0, float* __restrict__ out1,
    const float* __restrict__ bias,
    int M, int N, int K, int lda, int ldb, int ldc)
{
    constexpr int LDSK = BK + 8;   // 80B row stride: 16B-aligned, 2-way banks (free)
    constexpr int WM = BM / 2, WN = BN / 2;
    constexpr int FM = WM / 16, FN = WN / 16;
    __shared__ __align__(16) __bf16 As [BM * LDSK];
    __shared__ __align__(16) __bf16 As2[(AMODE == 2) ? BM * LDSK : 8];
    __shared__ __align__(16) __bf16 Bs [BN * LDSK];
    __shared__ __align__(16) __bf16 Bs2[(BMODE == 2) ? BN * LDSK : 8];

    const int tid  = threadIdx.x;
    const int lane = tid & 63;
    const int wid  = tid >> 6;
    const int wm = wid >> 1, wn = wid & 1;
    const int m0 = blockIdx.x * BM, n0 = blockIdx.y * BN;

    const int nkt = (K + BK - 1) / BK;
    const int per = (nkt + (int)gridDim.z - 1) / (int)gridDim.z;
    const int kb  = blockIdx.z * per * BK;
    const int ke  = min(K, kb + per * BK);

    f32x4 acc[FM][FN];
#pragma unroll
    for (int i = 0; i < FM; ++i)
#pragma unroll
        for (int j = 0; j < FN; ++j) acc[i][j] = f32x4{0.f, 0.f, 0.f, 0.f};

    const int fr = lane & 15, kq = lane >> 4;

    for (int kt = kb; kt < ke; kt += BK) {
        __syncthreads();
        // ---- stage A (BM x BK): f32 -> bf16 (hi[, lo]) ----
        {
            constexpr int CH = (BM * BK / 256) / 8;
#pragma unroll
            for (int i = 0; i < CH; ++i) {
                int c = tid * CH + i;
                int r = c / (BK / 8), kc = c % (BK / 8);
                const float* src = Ap + (size_t)(m0 + r) * lda + kt + kc * 8;
                f32x4 v0 = *(const f32x4*)src;
                f32x4 v1 = *(const f32x4*)(src + 4);
                bf16x8 hv;
#pragma unroll
                for (int e = 0; e < 4; ++e) {
                    hv[e]     = (__bf16)v0[e];
                    hv[4 + e] = (__bf16)v1[e];
                }
                *(bf16x8*)&As[r * LDSK + kc * 8] = hv;
                if constexpr (AMODE == 2) {
                    bf16x8 lv;
#pragma unroll
                    for (int e = 0; e < 4; ++e) {
                        lv[e]     = (__bf16)(v0[e] - (float)hv[e]);
                        lv[4 + e] = (__bf16)(v1[e] - (float)hv[4 + e]);
                    }
                    *(bf16x8*)&As2[r * LDSK + kc * 8] = lv;
                }
            }
        }
        // ---- stage B (BN x BK): f32 -> bf16 (hi[, lo]) ----
        {
            constexpr int CH = (BN * BK / 256) / 8;
#pragma unroll
            for (int i = 0; i < CH; ++i) {
                int c = tid * CH + i;
                int r = c / (BK / 8), kc = c % (BK / 8);
                const float* src = Bp + (size_t)(n0 + r) * ldb + kt + kc * 8;
                f32x4 v0 = *(const f32x4*)src;
                f32x4 v1 = *(const f32x4*)(src + 4);
                bf16x8 hv;
#pragma unroll
                for (int e = 0; e < 4; ++e) {
                    hv[e]     = (__bf16)v0[e];
                    hv[4 + e] = (__bf16)v1[e];
                }
                *(bf16x8*)&Bs[r * LDSK + kc * 8] = hv;
                if constexpr (BMODE == 2) {
                    bf16x8 lv;
#pragma unroll
                    for (int e = 0; e < 4; ++e) {
                        lv[e]     = (__bf16)(v0[e] - (float)hv[e]);
                        lv[4 + e] = (__bf16)(v1[e] - (float)hv[4 + e]);
                    }
                    *(bf16x8*)&Bs2[r * LDSK + kc * 8] = lv;
                }
            }
        }
        __syncthreads();
        // ---- fragments + MFMA ----
        bf16x8 af[FM], bfg[FN];
#pragma unroll
        for (int fm = 0; fm < FM; ++fm)
            af[fm] = *(const bf16x8*)&As[(wm * WM + fm * 16 + fr) * LDSK + kq * 8];
#pragma unroll
        for (int fn = 0; fn < FN; ++fn)
            bfg[fn] = *(const bf16x8*)&Bs[(wn * WN + fn * 16 + fr) * LDSK + kq * 8];
        if constexpr (AMODE == 2 && BMODE == 2) {
            bf16x8 al[FM], bl[FN];
#pragma unroll
            for (int fm = 0; fm < FM; ++fm)
                al[fm] = *(const bf16x8*)&As2[(wm * WM + fm * 16 + fr) * LDSK + kq * 8];
#pragma unroll
            for (int fn = 0; fn < FN; ++fn)
                bl[fn] = *(const bf16x8*)&Bs2[(wn * WN + fn * 16 + fr) * LDSK + kq * 8];
#pragma unroll
            for (int fm = 0; fm < FM; ++fm)
#pragma unroll
                for (int fn = 0; fn < FN; ++fn) {
                    acc[fm][fn] = __builtin_amdgcn_mfma_f32_16x16x32_bf16(
                        al[fm], bfg[fn], acc[fm][fn], 0, 0, 0);
                    acc[fm][fn] = __builtin_amdgcn_mfma_f32_16x16x32_bf16(
                        af[fm], bl[fn], acc[fm][fn], 0, 0, 0);
                    acc[fm][fn] = __builtin_amdgcn_mfma_f32_16x16x32_bf16(
                        af[fm], bfg[fn], acc[fm][fn], 0, 0, 0);
                }
        } else {
#pragma unroll
            for (int fm = 0; fm < FM; ++fm)
#pragma unroll
                for (int fn = 0; fn < FN; ++fn)
                    acc[fm][fn] = __builtin_amdgcn_mfma_f32_16x16x32_bf16(
                        af[fm], bfg[fn], acc[fm][fn], 0, 0, 0);
        }
    }

    const int rbase = m0 + wm * WM, cbase = n0 + wn * WN;
#pragma unroll
    for (int fm = 0; fm < FM; ++fm) {
#pragma unroll
        for (int fn = 0; fn < FN; ++fn) {
            int row = rbase + fm * 16 + (lane >> 4) * 4;
            int col = cbase + fn * 16 + (lane & 15);
            f32x4 v = acc[fm][fn];
            if (EPI == 0) {
                int split = N / 2;
                float* d = (col < split) ? out0 : out1;
                int cc = (col < split) ? col : col - split;
#pragma unroll
                for (int j = 0; j < 4; ++j) d[(size_t)(row + j) * ldc + cc] = v[j];
            } else if (EPI == 1) {
                float bz = bias[col];
#pragma unroll
                for (int j = 0; j < 4; ++j) {
                    float t = v[j] + bz;
                    t = (t > 20.f) ? t : log1pf(__expf(t));
                    out0[(size_t)(row + j) * ldc + col] = t;
                }
            } else if (EPI == 2) {
#pragma unroll
                for (int j = 0; j < 4; ++j)
                    atomicAdd(&out0[(size_t)(row + j) * ldc + col], v[j]);
            } else {
#pragma unroll
                for (int j = 0; j < 4; ++j) {
                    float t = v[j];
                    if (!(fabsf(t) < 1e30f)) t = 30000.0f;   // NaN/inf sentinel
                    out0[(size_t)(row + j) * ldc + col] = t;
                }
            }
        }
    }
}

// ---------------------------------------------------------------------------
__global__ __launch_bounds__(256) void zero_f32(float* __restrict__ p, int n4)
{
    int i = blockIdx.x * 256 + threadIdx.x;
    if (i < n4) ((f32x4*)p)[i] = f32x4{0.f, 0.f, 0.f, 0.f};
}

// ---------------------------------------------------------------------------
// Depthwise conv (width 4, left-pad 3) + SiLU.  x, xc: [L][D_INNER] f32.
// conv_state[d][j] = x[1020+j][d], f32.
// ---------------------------------------------------------------------------
__global__ __launch_bounds__(256) void conv_silu(
    const float* __restrict__ x, const float* __restrict__ cw,
    const float* __restrict__ cb, float* __restrict__ xc,
    float* __restrict__ conv_state)
{
    int idx = blockIdx.x * 256 + threadIdx.x;     // 1024*768 quads
    int l  = idx / (D_INNER / 4);
    int d4 = (idx % (D_INNER / 4)) * 4;
    const f32x4 zero = f32x4{0.f, 0.f, 0.f, 0.f};
    f32x4 x0 = *(const f32x4*)&x[(size_t)l * D_INNER + d4];
    f32x4 x1 = (l >= 1) ? *(const f32x4*)&x[(size_t)(l - 1) * D_INNER + d4] : zero;
    f32x4 x2 = (l >= 2) ? *(const f32x4*)&x[(size_t)(l - 2) * D_INNER + d4] : zero;
    f32x4 x3 = (l >= 3) ? *(const f32x4*)&x[(size_t)(l - 3) * D_INNER + d4] : zero;
    f32x4 r;
#pragma unroll
    for (int i = 0; i < 4; ++i) {
        int d = d4 + i;
        float w0 = cw[d * 4 + 0], w1 = cw[d * 4 + 1];
        float w2 = cw[d * 4 + 2], w3 = cw[d * 4 + 3];
        float v = cb[d] + w3 * x0[i] + w2 * x1[i] + w1 * x2[i] + w0 * x3[i];
        r[i] = v / (1.f + __expf(-v));
    }
    *(f32x4*)&xc[(size_t)l * D_INNER + d4] = r;
    if (l == L_SEQ - 1) {
#pragma unroll
        for (int i = 0; i < 4; ++i) {
            int d = d4 + i;
            conv_state[d * 4 + 3] = x0[i];
            conv_state[d * 4 + 2] = x1[i];
            conv_state[d * 4 + 1] = x2[i];
            conv_state[d * 4 + 0] = x3[i];
        }
    }
}

// ---------------------------------------------------------------------------
// Chunked selective scan, phase 1: per (chunk, d, n) local scan with h_in=0.
// Emits U[c][r] (local end state) and Aprod[c][r] (prod of dA over chunk).
// ---------------------------------------------------------------------------
__global__ __launch_bounds__(256) void scan_phase1(
    const float* __restrict__ delta, const float* __restrict__ xc,
    const float* __restrict__ dbl, const float* __restrict__ A_log,
    float* __restrict__ U, float* __restrict__ Aprod)
{
    int t = blockIdx.x * 256 + threadIdx.x;       // [0, NC*NCHAIN)
    int c = t / NCHAIN, r = t % NCHAIN;
    int d = r >> 4, n = r & 15;
    float a = __expf(A_log[d * D_STATE + n]);
    float h = 0.f, p = 1.f;
    int l0 = c * SCAN_CL;
    for (int i = 0; i < SCAN_CL; ++i) {
        int l = l0 + i;
        float dl  = delta[(size_t)l * D_INNER + d];
        float xcv = xc[(size_t)l * D_INNER + d];
        float Bv  = dbl[l * 128 + DT_RANK + n];
        float dA  = __expf(-dl * a);
        h = fmaf(dA, h, dl * Bv * xcv);
        p *= dA;
    }
    U[t] = h;
    Aprod[t] = p;
}

// ---------------------------------------------------------------------------
// Phase 2: per (d,n) serial combine over NC chunks -> h_in per chunk;
// also writes last_state ( = h after the final chunk ).
// ---------------------------------------------------------------------------
__global__ __launch_bounds__(256) void scan_phase2(
    const float* __restrict__ U, const float* __restrict__ Aprod,
    float* __restrict__ Hin, float* __restrict__ last_state)
{
    int r = blockIdx.x * 256 + threadIdx.x;       // [0, NCHAIN)
    float hin = 0.f;
#pragma unroll
    for (int c = 0; c < SCAN_NC; ++c) {
        Hin[c * NCHAIN + r] = hin;
        hin = fmaf(Aprod[c * NCHAIN + r], hin, U[c * NCHAIN + r]);
    }
    last_state[r] = hin;
}

// ---------------------------------------------------------------------------
// Phase 3: re-run local scan seeded with Hin; y = (sum_n h*C + D*xc)*silu(z).
// ---------------------------------------------------------------------------
__global__ __launch_bounds__(256) void scan_phase3(
    const float* __restrict__ delta, const float* __restrict__ xc,
    const float* __restrict__ z, const float* __restrict__ dbl,
    const float* __restrict__ A_log, const float* __restrict__ Dp,
    const float* __restrict__ Hin, float* __restrict__ y)
{
    int t = blockIdx.x * 256 + threadIdx.x;       // [0, NC*NCHAIN)
    int c = t / NCHAIN, r = t % NCHAIN;
    int d = r >> 4, n = r & 15;
    float a  = __expf(A_log[d * D_STATE + n]);
    float Dv = Dp[d];
    float h  = Hin[c * NCHAIN + r];
    int l0 = c * SCAN_CL;
    for (int i = 0; i < SCAN_CL; ++i) {
        int l = l0 + i;
        float dl  = delta[(size_t)l * D_INNER + d];
        float xcv = xc[(size_t)l * D_INNER + d];
        float Bv  = dbl[l * 128 + DT_RANK + n];
        float Cv  = dbl[l * 128 + DT_RANK + D_STATE + n];
        float dA  = __expf(-dl * a);
        h = fmaf(dA, h, dl * Bv * xcv);
        float yv = h * Cv;
        yv += __shfl_xor(yv, 8);
        yv += __shfl_xor(yv, 4);
        yv += __shfl_xor(yv, 2);
        yv += __shfl_xor(yv, 1);
        if (n == 0) {
            float zv = z[(size_t)l * D_INNER + d];
            float sz = zv / (1.f + __expf(-zv));
            y[(size_t)l * D_INNER + d] = (yv + Dv * xcv) * sz;
        }
    }
}

// ---------------------------------------------------------------------------
extern "C" void kernel_launch(void* const* d_in, const int* in_sizes, int n_in,
                              void* d_out, int out_size, void* d_ws, size_t ws_size,
                              hipStream_t stream)
{
    const float* hs    = (const float*)d_in[0];
    const float* Win   = (const float*)d_in[1];
    const float* cw    = (const float*)d_in[2];
    const float* cb    = (const float*)d_in[3];
    const float* Wx    = (const float*)d_in[4];
    const float* Wdt   = (const float*)d_in[5];
    const float* dtb   = (const float*)d_in[6];
    const float* Wout  = (const float*)d_in[7];
    const float* A_log = (const float*)d_in[8];
    const float* Dp    = (const float*)d_in[9];

    float* out        = (float*)d_out;                       // [1024][1536]
    float* conv_state = out + (size_t)L_SEQ * D_MODEL;       // [3072][4]
    float* last_state = conv_state + (size_t)D_INNER * 4;    // [3072][16]

    // Scratch: prefer d_ws when big enough; else static fallback.
    const size_t NEED = sizeof(float) * (size_t)SCRATCH_FLOATS;
    float* base;
    if (ws_size >= NEED) {
        base = (float*)d_ws;
    } else {
        void* sp = nullptr;
        hipGetSymbolAddress(&sp, HIP_SYMBOL(g_scratch));
        base = (float*)sp;
    }
    float* buf0 = base;                                // x -> delta
    float* buf1 = buf0 + (size_t)L_SEQ * D_INNER;      // z
    float* buf2 = buf1 + (size_t)L_SEQ * D_INNER;      // xc
    float* buf3 = buf2 + (size_t)L_SEQ * D_INNER;      // y
    float* dbl  = buf3 + (size_t)L_SEQ * D_INNER;      // [1024][128] dt|B|C
    float* Ubuf = dbl  + (size_t)L_SEQ * 128;          // [NC][NCHAIN]
    float* Abuf = Ubuf + (size_t)SCAN_NC * NCHAIN;     // [NC][NCHAIN]
    float* Hbuf = Abuf + (size_t)SCAN_NC * NCHAIN;     // [NC][NCHAIN]

    // zero dbl (atomic split-K target)
    zero_f32<<<dim3((L_SEQ * 128 / 4 + 255) / 256), 256, 0, stream>>>(dbl, L_SEQ * 128 / 4);

    // K1: xz = hs @ Win^T  -> x (buf0), z (buf1)
    gemm_bt<128, 128, 32, 1, 1, 0><<<dim3(8, 48, 1), 256, 0, stream>>>(
        hs, Win, buf0, buf1, nullptr, L_SEQ, 2 * D_INNER, D_MODEL, D_MODEL, D_MODEL, D_INNER);

    // K2: conv + silu -> xc (buf2); conv_state
    conv_silu<<<dim3(L_SEQ * D_INNER / 4 / 256), 256, 0, stream>>>(buf0, cw, cb, buf2, conv_state);

    // K3: x_dbl = xc @ Wx^T -> dbl (hi/lo both sides, split-K 12, atomic)
    gemm_bt<128, 128, 32, 2, 2, 2><<<dim3(8, 1, 12), 256, 0, stream>>>(
        buf2, Wx, dbl, nullptr, nullptr, L_SEQ, 128, D_INNER, D_INNER, D_INNER, 128);

    // K4: delta = softplus(dt @ Wdt^T + b) -> buf0 (x dead; hi/lo both sides)
    gemm_bt<128, 128, 32, 2, 2, 1><<<dim3(8, 24, 1), 256, 0, stream>>>(
        dbl, Wdt, buf0, nullptr, dtb, L_SEQ, D_INNER, DT_RANK, 128, DT_RANK, D_INNER);

    // K5: chunked scan (3 phases) -> y (buf3), last_state
    scan_phase1<<<dim3(SCAN_NC * NCHAIN / 256), 256, 0, stream>>>(
        buf0, buf2, dbl, A_log, Ubuf, Abuf);
    scan_phase2<<<dim3(NCHAIN / 256), 256, 0, stream>>>(
        Ubuf, Abuf, Hbuf, last_state);
    scan_phase3<<<dim3(SCAN_NC * NCHAIN / 256), 256, 0, stream>>>(
        buf0, buf2, buf1, dbl, A_log, Dp, Hbuf, buf3);

    // K7: out = y @ Wout^T -> f32 out (sentinel-scrubbed)
    gemm_bt<128, 64, 32, 1, 1, 3><<<dim3(8, 24, 1), 256, 0, stream>>>(
        buf3, Wout, out, nullptr, nullptr, L_SEQ, D_MODEL, D_INNER, D_INNER, D_INNER, D_MODEL);
}

// Round 7
// 289.353 us; speedup vs baseline: 3.2071x; 1.2137x over previous
//
#include <hip/hip_runtime.h>

using f32x4  = __attribute__((ext_vector_type(4))) float;
using bf16x8 = __attribute__((ext_vector_type(8))) __bf16;

#define L_SEQ 1024
#define D_MODEL 1536
#define D_INNER 3072
#define DT_RANK 96
#define D_STATE 16

#define SCAN_NC 16          // chunks over L
#define SCAN_CL (L_SEQ / SCAN_NC)
#define NCHAIN  (D_INNER * D_STATE)   // 49152 (d,n) chains

// Static fallback scratch: 4 x [1024][3072] + [1024][128] + 3 x [NC][49152] f32.
#define SCRATCH_FLOATS (4 * L_SEQ * D_INNER + L_SEQ * 128 + 3 * SCAN_NC * NCHAIN)
__device__ __align__(16) float g_scratch[SCRATCH_FLOATS];

// ---------------------------------------------------------------------------
// BT GEMM, all-f32 I/O: C[M][N] = sum_k A[M][K] * B[N][K]  (B is N-major f32)
// Register-prefetched: tile k+1's global loads are issued before tile k's
// MFMA phase, hiding HBM/L2 latency under compute.
// Staging converts f32 -> bf16 in LDS. AMODE/BMODE: 1 = plain bf16;
// 2 = (hi,lo) bf16 pair -> 3 MFMAs per k-tile (f32-accurate products).
// EPI: 0 = split store (x|z); 1 = softplus(acc+bias); 2 = atomicAdd (split-K);
//      3 = plain store; 4 = split-K partial slab store (out0 + z*M*ldc).
// ---------------------------------------------------------------------------
template <int BM, int BN, int BK, int AMODE, int BMODE, int EPI>
__global__ __launch_bounds__(256) void gemm_bt(
    const float* __restrict__ Ap, const float* __restrict__ Bp,
    float* __restrict__ out0, float* __restrict__ out1,
    const float* __restrict__ bias,
    int M, int N, int K, int lda, int ldb, int ldc)
{
    constexpr int LDSK = BK + 8;   // 80B row stride: 16B-aligned, 2-way banks (free)
    constexpr int WM = BM / 2, WN = BN / 2;
    constexpr int FM = WM / 16, FN = WN / 16;
    constexpr int CHA = (BM * BK / 256) / 8;   // 8-elem chunks per thread
    constexpr int CHB = (BN * BK / 256) / 8;
    __shared__ __align__(16) __bf16 As [BM * LDSK];
    __shared__ __align__(16) __bf16 As2[(AMODE == 2) ? BM * LDSK : 8];
    __shared__ __align__(16) __bf16 Bs [BN * LDSK];
    __shared__ __align__(16) __bf16 Bs2[(BMODE == 2) ? BN * LDSK : 8];

    const int tid  = threadIdx.x;
    const int lane = tid & 63;
    const int wid  = tid >> 6;
    const int wm = wid >> 1, wn = wid & 1;
    const int m0 = blockIdx.x * BM, n0 = blockIdx.y * BN;

    const int nkt = (K + BK - 1) / BK;
    const int per = (nkt + (int)gridDim.z - 1) / (int)gridDim.z;
    const int kb  = blockIdx.z * per * BK;
    const int ke  = min(K, kb + per * BK);

    f32x4 acc[FM][FN];
#pragma unroll
    for (int i = 0; i < FM; ++i)
#pragma unroll
        for (int j = 0; j < FN; ++j) acc[i][j] = f32x4{0.f, 0.f, 0.f, 0.f};

    const int fr = lane & 15, kq = lane >> 4;

    // register staging buffers (prefetch pipeline)
    f32x4 arg[CHA][2], brg[CHB][2];

    auto loadA = [&](int kt) {
#pragma unroll
        for (int i = 0; i < CHA; ++i) {
            int c = tid * CHA + i;
            int r = c / (BK / 8), kc = c % (BK / 8);
            const float* src = Ap + (size_t)(m0 + r) * lda + kt + kc * 8;
            arg[i][0] = *(const f32x4*)src;
            arg[i][1] = *(const f32x4*)(src + 4);
        }
    };
    auto loadB = [&](int kt) {
#pragma unroll
        for (int i = 0; i < CHB; ++i) {
            int c = tid * CHB + i;
            int r = c / (BK / 8), kc = c % (BK / 8);
            const float* src = Bp + (size_t)(n0 + r) * ldb + kt + kc * 8;
            brg[i][0] = *(const f32x4*)src;
            brg[i][1] = *(const f32x4*)(src + 4);
        }
    };
    auto writeA = [&]() {
#pragma unroll
        for (int i = 0; i < CHA; ++i) {
            int c = tid * CHA + i;
            int r = c / (BK / 8), kc = c % (BK / 8);
            bf16x8 hv;
#pragma unroll
            for (int e = 0; e < 4; ++e) {
                hv[e]     = (__bf16)arg[i][0][e];
                hv[4 + e] = (__bf16)arg[i][1][e];
            }
            *(bf16x8*)&As[r * LDSK + kc * 8] = hv;
            if constexpr (AMODE == 2) {
                bf16x8 lv;
#pragma unroll
                for (int e = 0; e < 4; ++e) {
                    lv[e]     = (__bf16)(arg[i][0][e] - (float)hv[e]);
                    lv[4 + e] = (__bf16)(arg[i][1][e] - (float)hv[4 + e]);
                }
                *(bf16x8*)&As2[r * LDSK + kc * 8] = lv;
            }
        }
    };
    auto writeB = [&]() {
#pragma unroll
        for (int i = 0; i < CHB; ++i) {
            int c = tid * CHB + i;
            int r = c / (BK / 8), kc = c % (BK / 8);
            bf16x8 hv;
#pragma unroll
            for (int e = 0; e < 4; ++e) {
                hv[e]     = (__bf16)brg[i][0][e];
                hv[4 + e] = (__bf16)brg[i][1][e];
            }
            *(bf16x8*)&Bs[r * LDSK + kc * 8] = hv;
            if constexpr (BMODE == 2) {
                bf16x8 lv;
#pragma unroll
                for (int e = 0; e < 4; ++e) {
                    lv[e]     = (__bf16)(brg[i][0][e] - (float)hv[e]);
                    lv[4 + e] = (__bf16)(brg[i][1][e] - (float)hv[4 + e]);
                }
                *(bf16x8*)&Bs2[r * LDSK + kc * 8] = lv;
            }
        }
    };

    loadA(kb);
    loadB(kb);

    for (int kt = kb; kt < ke; kt += BK) {
        writeA();                    // waits on in-flight loads (vmcnt)
        writeB();
        __syncthreads();             // LDS tile visible
        if (kt + BK < ke) {          // issue next tile's loads NOW;
            loadA(kt + BK);          // latency hides under MFMA below
            loadB(kt + BK);
        }
        // ---- fragments + MFMA ----
        bf16x8 af[FM], bfg[FN];
#pragma unroll
        for (int fm = 0; fm < FM; ++fm)
            af[fm] = *(const bf16x8*)&As[(wm * WM + fm * 16 + fr) * LDSK + kq * 8];
#pragma unroll
        for (int fn = 0; fn < FN; ++fn)
            bfg[fn] = *(const bf16x8*)&Bs[(wn * WN + fn * 16 + fr) * LDSK + kq * 8];
        if constexpr (AMODE == 2 && BMODE == 2) {
            bf16x8 al[FM], bl[FN];
#pragma unroll
            for (int fm = 0; fm < FM; ++fm)
                al[fm] = *(const bf16x8*)&As2[(wm * WM + fm * 16 + fr) * LDSK + kq * 8];
#pragma unroll
            for (int fn = 0; fn < FN; ++fn)
                bl[fn] = *(const bf16x8*)&Bs2[(wn * WN + fn * 16 + fr) * LDSK + kq * 8];
#pragma unroll
            for (int fm = 0; fm < FM; ++fm)
#pragma unroll
                for (int fn = 0; fn < FN; ++fn) {
                    acc[fm][fn] = __builtin_amdgcn_mfma_f32_16x16x32_bf16(
                        al[fm], bfg[fn], acc[fm][fn], 0, 0, 0);
                    acc[fm][fn] = __builtin_amdgcn_mfma_f32_16x16x32_bf16(
                        af[fm], bl[fn], acc[fm][fn], 0, 0, 0);
                    acc[fm][fn] = __builtin_amdgcn_mfma_f32_16x16x32_bf16(
                        af[fm], bfg[fn], acc[fm][fn], 0, 0, 0);
                }
        } else {
#pragma unroll
            for (int fm = 0; fm < FM; ++fm)
#pragma unroll
                for (int fn = 0; fn < FN; ++fn)
                    acc[fm][fn] = __builtin_amdgcn_mfma_f32_16x16x32_bf16(
                        af[fm], bfg[fn], acc[fm][fn], 0, 0, 0);
        }
        __syncthreads();             // reads done before next ds_write
    }

    const int rbase = m0 + wm * WM, cbase = n0 + wn * WN;
#pragma unroll
    for (int fm = 0; fm < FM; ++fm) {
#pragma unroll
        for (int fn = 0; fn < FN; ++fn) {
            int row = rbase + fm * 16 + (lane >> 4) * 4;
            int col = cbase + fn * 16 + (lane & 15);
            f32x4 v = acc[fm][fn];
            if (EPI == 0) {
                int split = N / 2;
                float* d = (col < split) ? out0 : out1;
                int cc = (col < split) ? col : col - split;
#pragma unroll
                for (int j = 0; j < 4; ++j) d[(size_t)(row + j) * ldc + cc] = v[j];
            } else if (EPI == 1) {
                float bz = bias[col];
#pragma unroll
                for (int j = 0; j < 4; ++j) {
                    float t = v[j] + bz;
                    t = (t > 20.f) ? t : log1pf(__expf(t));
                    out0[(size_t)(row + j) * ldc + col] = t;
                }
            } else if (EPI == 2) {
#pragma unroll
                for (int j = 0; j < 4; ++j)
                    atomicAdd(&out0[(size_t)(row + j) * ldc + col], v[j]);
            } else if (EPI == 3) {
#pragma unroll
                for (int j = 0; j < 4; ++j)
                    out0[(size_t)(row + j) * ldc + col] = v[j];
            } else {   // EPI == 4: split-K partial slab
                float* d = out0 + (size_t)blockIdx.z * M * ldc;
#pragma unroll
                for (int j = 0; j < 4; ++j)
                    d[(size_t)(row + j) * ldc + col] = v[j];
            }
        }
    }
}

// ---------------------------------------------------------------------------
__global__ __launch_bounds__(256) void zero_f32(float* __restrict__ p, int n4)
{
    int i = blockIdx.x * 256 + threadIdx.x;
    if (i < n4) ((f32x4*)p)[i] = f32x4{0.f, 0.f, 0.f, 0.f};
}

// out[i] = p[i] + p[slab + i]  (split-K=2 reduce), vectorized
__global__ __launch_bounds__(256) void reduce2_f32(
    const float* __restrict__ p, float* __restrict__ out, int n4)
{
    int i = blockIdx.x * 256 + threadIdx.x;
    if (i < n4) {
        f32x4 a = ((const f32x4*)p)[i];
        f32x4 b = ((const f32x4*)(p + (size_t)L_SEQ * D_MODEL))[i];
        ((f32x4*)out)[i] = a + b;
    }
}

// ---------------------------------------------------------------------------
// Depthwise conv (width 4, left-pad 3) + SiLU.  x, xc: [L][D_INNER] f32.
// conv_state[d][j] = x[1020+j][d], f32.
// ---------------------------------------------------------------------------
__global__ __launch_bounds__(256) void conv_silu(
    const float* __restrict__ x, const float* __restrict__ cw,
    const float* __restrict__ cb, float* __restrict__ xc,
    float* __restrict__ conv_state)
{
    int idx = blockIdx.x * 256 + threadIdx.x;     // 1024*768 quads
    int l  = idx / (D_INNER / 4);
    int d4 = (idx % (D_INNER / 4)) * 4;
    const f32x4 zero = f32x4{0.f, 0.f, 0.f, 0.f};
    f32x4 x0 = *(const f32x4*)&x[(size_t)l * D_INNER + d4];
    f32x4 x1 = (l >= 1) ? *(const f32x4*)&x[(size_t)(l - 1) * D_INNER + d4] : zero;
    f32x4 x2 = (l >= 2) ? *(const f32x4*)&x[(size_t)(l - 2) * D_INNER + d4] : zero;
    f32x4 x3 = (l >= 3) ? *(const f32x4*)&x[(size_t)(l - 3) * D_INNER + d4] : zero;
    f32x4 r;
#pragma unroll
    for (int i = 0; i < 4; ++i) {
        int d = d4 + i;
        float w0 = cw[d * 4 + 0], w1 = cw[d * 4 + 1];
        float w2 = cw[d * 4 + 2], w3 = cw[d * 4 + 3];
        float v = cb[d] + w3 * x0[i] + w2 * x1[i] + w1 * x2[i] + w0 * x3[i];
        r[i] = v / (1.f + __expf(-v));
    }
    *(f32x4*)&xc[(size_t)l * D_INNER + d4] = r;
    if (l == L_SEQ - 1) {
#pragma unroll
        for (int i = 0; i < 4; ++i) {
            int d = d4 + i;
            conv_state[d * 4 + 3] = x0[i];
            conv_state[d * 4 + 2] = x1[i];
            conv_state[d * 4 + 1] = x2[i];
            conv_state[d * 4 + 0] = x3[i];
        }
    }
}

// ---------------------------------------------------------------------------
// Chunked selective scan, phase 1: per (chunk, d, n) local scan with h_in=0.
// ---------------------------------------------------------------------------
__global__ __launch_bounds__(256) void scan_phase1(
    const float* __restrict__ delta, const float* __restrict__ xc,
    const float* __restrict__ dbl, const float* __restrict__ A_log,
    float* __restrict__ U, float* __restrict__ Aprod)
{
    int t = blockIdx.x * 256 + threadIdx.x;       // [0, NC*NCHAIN)
    int c = t / NCHAIN, r = t % NCHAIN;
    int d = r >> 4, n = r & 15;
    float a = __expf(A_log[d * D_STATE + n]);
    float h = 0.f, p = 1.f;
    int l0 = c * SCAN_CL;
    for (int i = 0; i < SCAN_CL; ++i) {
        int l = l0 + i;
        float dl  = delta[(size_t)l * D_INNER + d];
        float xcv = xc[(size_t)l * D_INNER + d];
        float Bv  = dbl[l * 128 + DT_RANK + n];
        float dA  = __expf(-dl * a);
        h = fmaf(dA, h, dl * Bv * xcv);
        p *= dA;
    }
    U[t] = h;
    Aprod[t] = p;
}

// ---------------------------------------------------------------------------
// Phase 2: per (d,n) serial combine over NC chunks -> h_in per chunk;
// also writes last_state.
// ---------------------------------------------------------------------------
__global__ __launch_bounds__(256) void scan_phase2(
    const float* __restrict__ U, const float* __restrict__ Aprod,
    float* __restrict__ Hin, float* __restrict__ last_state)
{
    int r = blockIdx.x * 256 + threadIdx.x;       // [0, NCHAIN)
    float hin = 0.f;
#pragma unroll
    for (int c = 0; c < SCAN_NC; ++c) {
        Hin[c * NCHAIN + r] = hin;
        hin = fmaf(Aprod[c * NCHAIN + r], hin, U[c * NCHAIN + r]);
    }
    last_state[r] = hin;
}

// ---------------------------------------------------------------------------
// Phase 3: re-run local scan seeded with Hin; y = (sum_n h*C + D*xc)*silu(z).
// ---------------------------------------------------------------------------
__global__ __launch_bounds__(256) void scan_phase3(
    const float* __restrict__ delta, const float* __restrict__ xc,
    const float* __restrict__ z, const float* __restrict__ dbl,
    const float* __restrict__ A_log, const float* __restrict__ Dp,
    const float* __restrict__ Hin, float* __restrict__ y)
{
    int t = blockIdx.x * 256 + threadIdx.x;       // [0, NC*NCHAIN)
    int c = t / NCHAIN, r = t % NCHAIN;
    int d = r >> 4, n = r & 15;
    float a  = __expf(A_log[d * D_STATE + n]);
    float Dv = Dp[d];
    float h  = Hin[c * NCHAIN + r];
    int l0 = c * SCAN_CL;
    for (int i = 0; i < SCAN_CL; ++i) {
        int l = l0 + i;
        float dl  = delta[(size_t)l * D_INNER + d];
        float xcv = xc[(size_t)l * D_INNER + d];
        float Bv  = dbl[l * 128 + DT_RANK + n];
        float Cv  = dbl[l * 128 + DT_RANK + D_STATE + n];
        float dA  = __expf(-dl * a);
        h = fmaf(dA, h, dl * Bv * xcv);
        float yv = h * Cv;
        yv += __shfl_xor(yv, 8);
        yv += __shfl_xor(yv, 4);
        yv += __shfl_xor(yv, 2);
        yv += __shfl_xor(yv, 1);
        if (n == 0) {
            float zv = z[(size_t)l * D_INNER + d];
            float sz = zv / (1.f + __expf(-zv));
            y[(size_t)l * D_INNER + d] = (yv + Dv * xcv) * sz;
        }
    }
}

// ---------------------------------------------------------------------------
extern "C" void kernel_launch(void* const* d_in, const int* in_sizes, int n_in,
                              void* d_out, int out_size, void* d_ws, size_t ws_size,
                              hipStream_t stream)
{
    const float* hs    = (const float*)d_in[0];
    const float* Win   = (const float*)d_in[1];
    const float* cw    = (const float*)d_in[2];
    const float* cb    = (const float*)d_in[3];
    const float* Wx    = (const float*)d_in[4];
    const float* Wdt   = (const float*)d_in[5];
    const float* dtb   = (const float*)d_in[6];
    const float* Wout  = (const float*)d_in[7];
    const float* A_log = (const float*)d_in[8];
    const float* Dp    = (const float*)d_in[9];

    float* out        = (float*)d_out;                       // [1024][1536]
    float* conv_state = out + (size_t)L_SEQ * D_MODEL;       // [3072][4]
    float* last_state = conv_state + (size_t)D_INNER * 4;    // [3072][16]

    // Scratch: prefer d_ws when big enough; else static fallback.
    const size_t NEED = sizeof(float) * (size_t)SCRATCH_FLOATS;
    float* base;
    if (ws_size >= NEED) {
        base = (float*)d_ws;
    } else {
        void* sp = nullptr;
        hipGetSymbolAddress(&sp, HIP_SYMBOL(g_scratch));
        base = (float*)sp;
    }
    float* buf0 = base;                                // x -> delta -> K7 partials
    float* buf1 = buf0 + (size_t)L_SEQ * D_INNER;      // z
    float* buf2 = buf1 + (size_t)L_SEQ * D_INNER;      // xc
    float* buf3 = buf2 + (size_t)L_SEQ * D_INNER;      // y
    float* dbl  = buf3 + (size_t)L_SEQ * D_INNER;      // [1024][128] dt|B|C
    float* Ubuf = dbl  + (size_t)L_SEQ * 128;          // [NC][NCHAIN]
    float* Abuf = Ubuf + (size_t)SCAN_NC * NCHAIN;     // [NC][NCHAIN]
    float* Hbuf = Abuf + (size_t)SCAN_NC * NCHAIN;     // [NC][NCHAIN]

    // zero dbl (atomic split-K target)
    zero_f32<<<dim3((L_SEQ * 128 / 4 + 255) / 256), 256, 0, stream>>>(dbl, L_SEQ * 128 / 4);

    // K1: xz = hs @ Win^T  -> x (buf0), z (buf1)
    gemm_bt<128, 128, 32, 1, 1, 0><<<dim3(8, 48, 1), 256, 0, stream>>>(
        hs, Win, buf0, buf1, nullptr, L_SEQ, 2 * D_INNER, D_MODEL, D_MODEL, D_MODEL, D_INNER);

    // K2: conv + silu -> xc (buf2); conv_state
    conv_silu<<<dim3(L_SEQ * D_INNER / 4 / 256), 256, 0, stream>>>(buf0, cw, cb, buf2, conv_state);

    // K3: x_dbl = xc @ Wx^T -> dbl (hi/lo both sides, split-K 12, atomic)
    gemm_bt<128, 128, 32, 2, 2, 2><<<dim3(8, 1, 12), 256, 0, stream>>>(
        buf2, Wx, dbl, nullptr, nullptr, L_SEQ, 128, D_INNER, D_INNER, D_INNER, 128);

    // K4: delta = softplus(dt @ Wdt^T + b) -> buf0 (x dead; hi/lo both sides)
    gemm_bt<128, 128, 32, 2, 2, 1><<<dim3(8, 24, 1), 256, 0, stream>>>(
        dbl, Wdt, buf0, nullptr, dtb, L_SEQ, D_INNER, DT_RANK, 128, DT_RANK, D_INNER);

    // K5: chunked scan (3 phases) -> y (buf3), last_state
    scan_phase1<<<dim3(SCAN_NC * NCHAIN / 256), 256, 0, stream>>>(
        buf0, buf2, dbl, A_log, Ubuf, Abuf);
    scan_phase2<<<dim3(NCHAIN / 256), 256, 0, stream>>>(
        Ubuf, Abuf, Hbuf, last_state);
    scan_phase3<<<dim3(SCAN_NC * NCHAIN / 256), 256, 0, stream>>>(
        buf0, buf2, buf1, dbl, A_log, Dp, Hbuf, buf3);

    // K7: out = y @ Wout^T, split-K=2 partials into buf0 (delta dead), then reduce
    gemm_bt<128, 64, 32, 1, 1, 4><<<dim3(8, 24, 2), 256, 0, stream>>>(
        buf3, Wout, buf0, nullptr, nullptr, L_SEQ, D_MODEL, D_INNER, D_INNER, D_INNER, D_MODEL);
    reduce2_f32<<<dim3(L_SEQ * D_MODEL / 4 / 256), 256, 0, stream>>>(
        buf0, out, L_SEQ * D_MODEL / 4);
}